// Round 7
// baseline (287.027 us; speedup 1.0000x reference)
//
#include <hip/hip_runtime.h>

#define NB    16
#define NCH   512
#define NCOL  16384
#define NPTS  4096

// Barrier rule for bitonic passes, element mapping i ≡ tid (mod 1024):
//   j >= 1024 : pair is same-thread          -> no barrier
//   j <  64   : partner thread in same wave  -> no barrier (per-wave DS
//               ops are processed in order — HW-validated R3-R6, absmax 0)
//   else      : cross-wave -> __syncthreads(). Conservative lower edge 32.
#define PASS_SYNC(j) do { if ((j) >= 32 && (j) < 1024) __syncthreads(); } while (0)

// ---------------------------------------------------------------------------
// Phase 1: z[b][i] = max_c y[b][c][i] as 64-bit descending key:
//   key = (sortable_uint(z) << 32) | (16383 - i)   (unique -> total order;
//   desc sort == value desc, index asc == lax.top_k tie-breaking)
// Occupancy: 256-col tile per block; wave w reduces channels 128w..128w+127,
// 4 KiB LDS cross-wave reduce. 1024 blocks -> 4 waves/SIMD (vs 1 before),
// zero extra HBM traffic.
// ---------------------------------------------------------------------------
__global__ __launch_bounds__(256) void max_key_kernel(
        const float* __restrict__ y, unsigned long long* __restrict__ keys) {
    __shared__ float4 part[4][64];   // 4 KiB
    unsigned w = threadIdx.x >> 6, l = threadIdx.x & 63u;
    unsigned col = blockIdx.x * 256u + (l << 2);    // float4 base column
    unsigned b = blockIdx.y;
    const float* p = y + ((size_t)b << 23) + ((size_t)(w << 7) << 14) + col;
    float4 m = *(const float4*)p;
    #pragma unroll 8
    for (int c = 1; c < NCH / 4; ++c) {
        float4 v = *(const float4*)(p + ((size_t)c << 14));
        m.x = fmaxf(m.x, v.x); m.y = fmaxf(m.y, v.y);
        m.z = fmaxf(m.z, v.z); m.w = fmaxf(m.w, v.w);
    }
    part[w][l] = m;
    __syncthreads();
    if (w == 0) {
        float4 p0 = part[0][l], p1 = part[1][l], p2 = part[2][l], p3 = part[3][l];
        float mv[4] = {
            fmaxf(fmaxf(p0.x, p1.x), fmaxf(p2.x, p3.x)),
            fmaxf(fmaxf(p0.y, p1.y), fmaxf(p2.y, p3.y)),
            fmaxf(fmaxf(p0.z, p1.z), fmaxf(p2.z, p3.z)),
            fmaxf(fmaxf(p0.w, p1.w), fmaxf(p2.w, p3.w))};
        unsigned long long* kp = keys + ((size_t)b << 14) + col;
        #pragma unroll
        for (int q = 0; q < 4; ++q) {
            unsigned u = __float_as_uint(mv[q]);
            unsigned s = (u & 0x80000000u) ? ~u : (u | 0x80000000u);
            kp[q] = ((unsigned long long)s << 32) |
                    (unsigned long long)(16383u - (col + q));
        }
    }
}

// ---------------------------------------------------------------------------
// Phase 2a: sort each 2048-chunk descending (bitonic, LDS), in place.
// 8 chunks/batch x 16 batches = 128 blocks.
// ---------------------------------------------------------------------------
__global__ __launch_bounds__(1024) void chunk_sort_kernel(
        unsigned long long* __restrict__ keys) {
    __shared__ unsigned long long sk[2048];   // 16 KiB
    unsigned tid = threadIdx.x;
    unsigned b = blockIdx.x >> 3, ch = blockIdx.x & 7;
    unsigned long long* gk = keys + ((size_t)b << 14) + ((size_t)ch << 11);

    sk[tid] = gk[tid];
    sk[tid + 1024] = gk[tid + 1024];
    __syncthreads();
    for (unsigned k = 2; k <= 2048; k <<= 1) {
        for (unsigned j = k >> 1; j > 0; j >>= 1) {
            PASS_SYNC(j);
            #pragma unroll
            for (unsigned s = 0; s < 2; ++s) {
                unsigned i = tid + (s << 10);
                unsigned ixj = i ^ j;
                if (ixj > i) {
                    unsigned long long a = sk[i], c2 = sk[ixj];
                    bool sw = ((i & k) == 0) ? (a < c2) : (a > c2);
                    if (sw) { sk[i] = c2; sk[ixj] = a; }
                }
            }
        }
    }
    __syncthreads();
    gk[tid] = sk[tid];
    gk[tid + 1024] = sk[tid + 1024];
}

// ---------------------------------------------------------------------------
// Phase 2b/c: merge-path merge of two sorted-desc lists A,B (length L, at
// src + task*2L and + L), emitting top NPTS of the merge, sorted desc.
// 256 thr/task, 16 outputs/thread: diagonal binary search + serial merge.
// All keys distinct -> strict compares, exact tie order. No barriers.
// ---------------------------------------------------------------------------
__global__ __launch_bounds__(256) void merge_path_kernel(
        const unsigned long long* __restrict__ src,
        unsigned long long* __restrict__ dst, unsigned L) {
    unsigned task = blockIdx.x;
    const unsigned long long* A = src + (size_t)task * (L << 1);
    const unsigned long long* B = A + L;
    unsigned p = threadIdx.x << 4;

    unsigned lo = (p > L) ? (p - L) : 0u;
    unsigned hi = (p < L) ? p : L;
    while (lo < hi) {
        unsigned mid = (lo + hi) >> 1;
        if (A[mid] < B[p - 1 - mid]) hi = mid; else lo = mid + 1;
    }
    unsigned a = lo, b = p - lo;

    unsigned long long av = (a < L) ? A[a] : 0ull;
    unsigned long long bv = (b < L) ? B[b] : 0ull;
    #pragma unroll
    for (unsigned q = 0; q < 16; ++q) {
        bool ta = (b >= L) || (a < L && av > bv);
        unsigned long long o = ta ? av : bv;
        if (ta) { ++a; av = (a < L) ? A[a] : 0ull; }
        else    { ++b; bv = (b < L) ? B[b] : 0ull; }
        dst[(size_t)task * NPTS + p + q] = o;
    }
}

// ---------------------------------------------------------------------------
// Phase 2d: final merge level, fused with the x-gather. Block b produces
// idx[b] (each thread holds its 16 indices in registers) and immediately
// gathers x (3 rows, 192 KiB/batch — L2-resident) writing coalesced f4.
// ---------------------------------------------------------------------------
__global__ __launch_bounds__(256) void merge_final_kernel(
        const unsigned long long* __restrict__ src, int* __restrict__ idx,
        const float* __restrict__ x, float* __restrict__ outx) {
    const unsigned L = 4096;
    unsigned task = blockIdx.x;                    // batch
    const unsigned long long* A = src + (size_t)task * (L << 1);
    const unsigned long long* B = A + L;
    unsigned p = threadIdx.x << 4;

    unsigned lo = (p > L) ? (p - L) : 0u;
    unsigned hi = (p < L) ? p : L;
    while (lo < hi) {
        unsigned mid = (lo + hi) >> 1;
        if (A[mid] < B[p - 1 - mid]) hi = mid; else lo = mid + 1;
    }
    unsigned a = lo, b = p - lo;

    int my[16];
    unsigned long long av = (a < L) ? A[a] : 0ull;
    unsigned long long bv = (b < L) ? B[b] : 0ull;
    #pragma unroll
    for (unsigned q = 0; q < 16; ++q) {
        bool ta = (b >= L) || (a < L && av > bv);
        unsigned long long o = ta ? av : bv;
        if (ta) { ++a; av = (a < L) ? A[a] : 0ull; }
        else    { ++b; bv = (b < L) ? B[b] : 0ull; }
        my[q] = (int)(16383u - (unsigned)(o & 0xFFFFFFFFull));
        idx[(size_t)task * NPTS + p + q] = my[q];
    }
    // fused x-gather: out[(b*3+c)][p..p+15]
    const float* xb = x + (((size_t)task * 3u) << 14);
    #pragma unroll
    for (unsigned c = 0; c < 3; ++c) {
        float v[16];
        #pragma unroll
        for (unsigned q = 0; q < 16; ++q)
            v[q] = xb[((size_t)c << 14) + (unsigned)my[q]];
        float* orow = outx + ((size_t)task * 3u + c) * NPTS + p;
        #pragma unroll
        for (unsigned q = 0; q < 4; ++q)
            *(float4*)(orow + (q << 2)) =
                make_float4(v[q * 4], v[q * 4 + 1], v[q * 4 + 2], v[q * 4 + 3]);
    }
}

// ---------------------------------------------------------------------------
// Phase 3: LDS-staged y row gather: 1024 thr + 64 KiB LDS -> 2 blocks/CU.
// Both global sides fully coalesced.
// ---------------------------------------------------------------------------
__global__ __launch_bounds__(1024) void row_gather_kernel(
        const float* __restrict__ src, const int* __restrict__ idx,
        float* __restrict__ out) {
    __shared__ float row[NCOL];   // 64 KiB
    unsigned bc = blockIdx.x;             // b*NCH + c
    unsigned b  = bc >> 9;
    const float4* sv = (const float4*)(src + ((size_t)bc << 14));
    float4* rv = (float4*)row;
    #pragma unroll
    for (unsigned i = threadIdx.x; i < NCOL / 4; i += 1024) rv[i] = sv[i];
    __syncthreads();
    const int* ib = idx + (b << 12);
    float* orow = out + (size_t)bc * NPTS;
    unsigned j = threadIdx.x << 2;
    int4 iv = *(const int4*)(ib + j);
    float4 ov;
    ov.x = row[iv.x]; ov.y = row[iv.y];
    ov.z = row[iv.z]; ov.w = row[iv.w];
    *(float4*)(orow + j) = ov;
}

extern "C" void kernel_launch(void* const* d_in, const int* in_sizes, int n_in,
                              void* d_out, int out_size, void* d_ws, size_t ws_size,
                              hipStream_t stream) {
    const float* x = (const float*)d_in[0];
    const float* y = (const float*)d_in[1];
    float* out = (float*)d_out;

    char* ws = (char*)d_ws;
    unsigned long long* keys  = (unsigned long long*)ws;                // 2 MiB
    unsigned long long* keys2 = (unsigned long long*)(ws + (2u << 20)); // 2 MiB
    int* idx = (int*)(ws + (4u << 20));                                 // 256 KiB

    // 1) per-column channel max -> u64 keys (4 waves/SIMD)
    max_key_kernel<<<dim3(NCOL / 256, NB), 256, 0, stream>>>(y, keys);
    // 2) sort 2048-chunks descending in place (128 blocks)
    chunk_sort_kernel<<<NB * 8, 1024, 0, stream>>>(keys);
    // 3) merge tree (exact top-4096 truncation per level)
    merge_path_kernel<<<NB * 4, 256, 0, stream>>>(keys, keys2, 2048);
    merge_path_kernel<<<NB * 2, 256, 0, stream>>>(keys2, keys, 4096);
    //    final level fused with x-gather
    merge_final_kernel<<<NB, 256, 0, stream>>>(keys, idx, x, out);
    // 4) big y-gather
    row_gather_kernel<<<NB * NCH, 1024, 0, stream>>>(
        y, idx, out + (size_t)NB * 3 * NPTS);
}

// Round 8
// 255.524 us; speedup vs baseline: 1.1233x; 1.1233x over previous
//
#include <hip/hip_runtime.h>

#define NB    16
#define NCH   512
#define NCOL  16384
#define NPTS  4096

// Barrier rule for bitonic passes, element mapping i ≡ tid (mod 1024):
//   j >= 1024 : pair is same-thread          -> no barrier
//   j <  64   : partner thread in same wave  -> no barrier (per-wave DS
//               ops are processed in order — HW-validated R3-R7, absmax 0)
//   else      : cross-wave -> __syncthreads(). Conservative lower edge 32.
#define PASS_SYNC(j) do { if ((j) >= 32 && (j) < 1024) __syncthreads(); } while (0)

// ---------------------------------------------------------------------------
// Phase 1: z[b][i] = max_c y[b][c][i] as 64-bit descending key:
//   key = (sortable_uint(z) << 32) | (16383 - i)   (unique -> total order;
//   desc sort == value desc, index asc == lax.top_k tie-breaking)
// R5-proven form: thread owns 4 columns, float4 loads, 512-deep max chain.
// ---------------------------------------------------------------------------
__global__ void max_key_kernel(const float* __restrict__ y,
                               unsigned long long* __restrict__ keys) {
    unsigned t = blockIdx.x * 256u + threadIdx.x;   // 0..4095 per batch
    unsigned b = blockIdx.y;
    unsigned i = t << 2;
    const float* p = y + ((size_t)b << 23) + i;
    float4 m = *(const float4*)p;
    #pragma unroll 8
    for (int c = 1; c < NCH; ++c) {
        float4 v = *(const float4*)(p + ((size_t)c << 14));
        m.x = fmaxf(m.x, v.x); m.y = fmaxf(m.y, v.y);
        m.z = fmaxf(m.z, v.z); m.w = fmaxf(m.w, v.w);
    }
    unsigned long long* kp = keys + ((size_t)b << 14) + i;
    float mv[4] = {m.x, m.y, m.z, m.w};
    #pragma unroll
    for (int q = 0; q < 4; ++q) {
        unsigned u = __float_as_uint(mv[q]);
        unsigned s = (u & 0x80000000u) ? ~u : (u | 0x80000000u);
        kp[q] = ((unsigned long long)s << 32) |
                (unsigned long long)(16383u - (i + q));
    }
}

// ---------------------------------------------------------------------------
// Phase 2a: sort each 2048-chunk descending (bitonic, LDS), in place.
// 8 chunks/batch x 16 batches = 128 blocks.
// ---------------------------------------------------------------------------
__global__ __launch_bounds__(1024) void chunk_sort_kernel(
        unsigned long long* __restrict__ keys) {
    __shared__ unsigned long long sk[2048];   // 16 KiB
    unsigned tid = threadIdx.x;
    unsigned b = blockIdx.x >> 3, ch = blockIdx.x & 7;
    unsigned long long* gk = keys + ((size_t)b << 14) + ((size_t)ch << 11);

    sk[tid] = gk[tid];
    sk[tid + 1024] = gk[tid + 1024];
    __syncthreads();
    for (unsigned k = 2; k <= 2048; k <<= 1) {
        for (unsigned j = k >> 1; j > 0; j >>= 1) {
            PASS_SYNC(j);
            #pragma unroll
            for (unsigned s = 0; s < 2; ++s) {
                unsigned i = tid + (s << 10);
                unsigned ixj = i ^ j;
                if (ixj > i) {
                    unsigned long long a = sk[i], c2 = sk[ixj];
                    bool sw = ((i & k) == 0) ? (a < c2) : (a > c2);
                    if (sw) { sk[i] = c2; sk[ixj] = a; }
                }
            }
        }
    }
    __syncthreads();
    gk[tid] = sk[tid];
    gk[tid + 1024] = sk[tid + 1024];
}

// ---------------------------------------------------------------------------
// Phase 2b: fused 3-level merge tree, one block per batch (1024 thr,
// 128 KiB LDS). Merge-path at every level (unique keys -> strict compares,
// exact lax.top_k tie order):
//   L1: 4 tasks (2048,2048)->4096 full merge, global keys -> LDS
//   L2: 2 tasks top-4096 of (4096,4096), LDS -> regs -> LDS (barriered)
//   L3: 1 task  top-4096 of (4096,4096), LDS -> decoded idx (int4 store)
// ---------------------------------------------------------------------------
__global__ __launch_bounds__(1024) void merge_all_kernel(
        const unsigned long long* __restrict__ keys, int* __restrict__ idx) {
    __shared__ unsigned long long s0[16384];   // 128 KiB
    unsigned tid = threadIdx.x;
    unsigned bt  = blockIdx.x;
    const unsigned long long* gk = keys + ((size_t)bt << 14);

    // ---- L1: global -> LDS, full merges
    {
        unsigned task = tid >> 8;              // 0..3
        unsigned t    = tid & 255u;
        const unsigned L = 2048;
        const unsigned long long* A = gk + (task << 12);
        const unsigned long long* B = A + L;
        unsigned p = t << 4;                   // 16 outputs/thread
        unsigned lo = (p > L) ? (p - L) : 0u;
        unsigned hi = (p < L) ? p : L;
        while (lo < hi) {
            unsigned mid = (lo + hi) >> 1;
            if (A[mid] < B[p - 1 - mid]) hi = mid; else lo = mid + 1;
        }
        unsigned a = lo, b = p - lo;
        unsigned long long av = (a < L) ? A[a] : 0ull;
        unsigned long long bv = (b < L) ? B[b] : 0ull;
        unsigned long long* dst = s0 + (task << 12) + p;
        #pragma unroll
        for (unsigned q = 0; q < 16; ++q) {
            bool ta = (b >= L) || (a < L && av > bv);
            unsigned long long o = ta ? av : bv;
            if (ta) { ++a; av = (a < L) ? A[a] : 0ull; }
            else    { ++b; bv = (b < L) ? B[b] : 0ull; }
            dst[q] = o;
        }
    }
    __syncthreads();

    // ---- L2: LDS -> regs (top-4096 per task), then barriered write-back
    unsigned long long r[8];
    unsigned task2 = tid >> 9;                 // 0..1
    unsigned t2    = tid & 511u;
    {
        const unsigned L = 4096;
        const unsigned long long* A = s0 + (task2 << 13);
        const unsigned long long* B = A + L;
        unsigned p = t2 << 3;                  // 8 outputs/thread
        unsigned lo = (p > L) ? (p - L) : 0u;
        unsigned hi = (p < L) ? p : L;
        while (lo < hi) {
            unsigned mid = (lo + hi) >> 1;
            if (A[mid] < B[p - 1 - mid]) hi = mid; else lo = mid + 1;
        }
        unsigned a = lo, b = p - lo;
        unsigned long long av = (a < L) ? A[a] : 0ull;
        unsigned long long bv = (b < L) ? B[b] : 0ull;
        #pragma unroll
        for (unsigned q = 0; q < 8; ++q) {
            bool ta = (b >= L) || (a < L && av > bv);
            r[q] = ta ? av : bv;
            if (ta) { ++a; av = (a < L) ? A[a] : 0ull; }
            else    { ++b; bv = (b < L) ? B[b] : 0ull; }
        }
    }
    __syncthreads();                            // all reads done
    {
        unsigned long long* dst = s0 + (task2 << 12) + (t2 << 3);
        #pragma unroll
        for (unsigned q = 0; q < 8; ++q) dst[q] = r[q];
    }
    __syncthreads();                            // all writes visible

    // ---- L3: LDS -> decoded idx
    {
        const unsigned L = 4096;
        const unsigned long long* A = s0;
        const unsigned long long* B = s0 + L;
        unsigned p = tid << 2;                  // 4 outputs/thread
        unsigned lo = (p > L) ? (p - L) : 0u;
        unsigned hi = (p < L) ? p : L;
        while (lo < hi) {
            unsigned mid = (lo + hi) >> 1;
            if (A[mid] < B[p - 1 - mid]) hi = mid; else lo = mid + 1;
        }
        unsigned a = lo, b = p - lo;
        unsigned long long av = (a < L) ? A[a] : 0ull;
        unsigned long long bv = (b < L) ? B[b] : 0ull;
        int o4[4];
        #pragma unroll
        for (unsigned q = 0; q < 4; ++q) {
            bool ta = (b >= L) || (a < L && av > bv);
            unsigned long long o = ta ? av : bv;
            if (ta) { ++a; av = (a < L) ? A[a] : 0ull; }
            else    { ++b; bv = (b < L) ? B[b] : 0ull; }
            o4[q] = (int)(16383u - (unsigned)(o & 0xFFFFFFFFull));
        }
        *(int4*)(idx + ((size_t)bt << 12) + p) =
            make_int4(o4[0], o4[1], o4[2], o4[3]);
    }
}

// ---------------------------------------------------------------------------
// Phase 3: LDS-staged row gather: 1024 thr + 64 KiB LDS -> 2 blocks/CU.
// Both global sides fully coalesced.
// ---------------------------------------------------------------------------
__global__ __launch_bounds__(1024) void row_gather_kernel(
        const float* __restrict__ src, const int* __restrict__ idx,
        float* __restrict__ out, int nch) {
    __shared__ float row[NCOL];   // 64 KiB
    unsigned bc = blockIdx.x;             // b*nch + c
    unsigned b  = bc / (unsigned)nch;
    const float4* sv = (const float4*)(src + ((size_t)bc << 14));
    float4* rv = (float4*)row;
    #pragma unroll
    for (unsigned i = threadIdx.x; i < NCOL / 4; i += 1024) rv[i] = sv[i];
    __syncthreads();
    const int* ib = idx + (b << 12);
    float* orow = out + (size_t)bc * NPTS;
    unsigned j = threadIdx.x << 2;
    int4 iv = *(const int4*)(ib + j);
    float4 ov;
    ov.x = row[iv.x]; ov.y = row[iv.y];
    ov.z = row[iv.z]; ov.w = row[iv.w];
    *(float4*)(orow + j) = ov;
}

extern "C" void kernel_launch(void* const* d_in, const int* in_sizes, int n_in,
                              void* d_out, int out_size, void* d_ws, size_t ws_size,
                              hipStream_t stream) {
    const float* x = (const float*)d_in[0];
    const float* y = (const float*)d_in[1];
    float* out = (float*)d_out;

    char* ws = (char*)d_ws;
    unsigned long long* keys = (unsigned long long*)ws;   // 2 MiB
    int* idx = (int*)(ws + (4u << 20));                   // 256 KiB

    // 1) per-column channel max -> u64 keys
    max_key_kernel<<<dim3(NCOL / 4 / 256, NB), 256, 0, stream>>>(y, keys);
    // 2) sort 2048-chunks descending in place (128 blocks)
    chunk_sort_kernel<<<NB * 8, 1024, 0, stream>>>(keys);
    // 3) fused 3-level merge tree -> idx (16 blocks)
    merge_all_kernel<<<NB, 1024, 0, stream>>>(keys, idx);
    // 4) gathers (both sides coalesced via LDS staging)
    row_gather_kernel<<<NB * 3, 1024, 0, stream>>>(x, idx, out, 3);
    row_gather_kernel<<<NB * NCH, 1024, 0, stream>>>(
        y, idx, out + (size_t)NB * 3 * NPTS, NCH);
}